// Round 4
// baseline (239.511 us; speedup 1.0000x reference)
//
#include <hip/hip_runtime.h>
#include <math.h>

#define DD 2048   // hidden dim
#define EE 16     // experts
#define RR 16     // lora rank
#define QO 2048   // q out dim
#define VO 512    // v out dim
#define TILE 128  // tokens per A-side tile
#define BATCH 16  // tokens per inner batch (A-side)
#define T2 32     // B-side tokens per tile
#define CGQ 8     // q column groups (256 cols each)
#define CGV 2     // v column groups
#define RTB 4     // router tokens per block
#define RDC 256   // router D-chunk

struct Route { int i0, i1; float w0, w1; };

// ---------------- K1: router (fp64 logits -> top-2 weights) ----------------
__global__ __launch_bounds__(256) void router_kernel(
    const float* __restrict__ h, const float* __restrict__ rw,
    Route* __restrict__ route, int n)
{
    __shared__ float  hs[RTB * RDC];     // 4 KB
    __shared__ double slogd[RTB * EE];

    int t0 = blockIdx.x * RTB;
    int e  = threadIdx.x >> 4;
    int l  = threadIdx.x & 15;

    double acc[RTB] = {0.0, 0.0, 0.0, 0.0};

    for (int d0 = 0; d0 < DD; d0 += RDC) {
        __syncthreads();
        {   // RTB*RDC/4 == 256 float4 tasks == 1/thread
            int t = threadIdx.x >> 6, dq = (threadIdx.x & 63) * 4;
            float4 v = make_float4(0.f, 0.f, 0.f, 0.f);
            if (t0 + t < n)
                v = *(const float4*)&h[(size_t)(t0 + t) * DD + d0 + dq];
            *(float4*)&hs[t * RDC + dq] = v;
        }
        __syncthreads();
        const float* rwe = rw + e * DD + d0;
#pragma unroll
        for (int g = 0; g < RDC / 64; ++g) {
            int d = g * 64 + l * 4;
            float4 r4 = *(const float4*)&rwe[d];
            double rx = r4.x, ry = r4.y, rz = r4.z, rw4 = r4.w;
#pragma unroll
            for (int t = 0; t < RTB; ++t) {
                float4 hv = *(const float4*)&hs[t * RDC + d];
                acc[t] += (double)hv.x * rx + (double)hv.y * ry
                        + (double)hv.z * rz + (double)hv.w * rw4;
            }
        }
    }
#pragma unroll
    for (int t = 0; t < RTB; ++t) {
#pragma unroll
        for (int off = 8; off; off >>= 1)
            acc[t] += __shfl_down(acc[t], off, 16);
    }
    if (l == 0) {
#pragma unroll
        for (int t = 0; t < RTB; ++t) slogd[t * EE + e] = acc[t];
    }
    __syncthreads();

    if (threadIdx.x < RTB) {
        int t = threadIdx.x, tok = t0 + t;
        if (tok < n) {
            double lg[EE];
#pragma unroll
            for (int i = 0; i < EE; ++i) lg[i] = slogd[t * EE + i];
            int i0 = 0;
            for (int i = 1; i < EE; ++i) if (lg[i] > lg[i0]) i0 = i;
            int i1 = -1;
            for (int i = 0; i < EE; ++i)
                if (i != i0 && (i1 < 0 || lg[i] > lg[i1])) i1 = i;
            double mx = lg[i0], Z = 0.0;
            for (int i = 0; i < EE; ++i) Z += exp(lg[i] - mx);
            double p0 = 1.0 / Z;
            double p1 = exp(lg[i1] - mx) / Z;
            double s  = p0 + p1 + 1e-20;
            Route rt;
            rt.i0 = i0; rt.i1 = i1;
            rt.w0 = (float)(2.0 * p0 / s);   // scale = ALPHA/R = 2
            rt.w1 = (float)(2.0 * p1 / s);
            route[tok] = rt;
        }
    }
}

// ---------------- K2: A-side partials, barrier-light ----------------
// grid (EE, tiles, DSPLIT). a staged ONCE per block; h per 16-token batch;
// compute loop has no internal barriers. low[(tok*2+k)*DSPLIT*32 + ds*32 + ...]
template<int DSPLIT, bool TWOPASS>
__global__ __launch_bounds__(256) void a_kernel(
    const float* __restrict__ h, const Route* __restrict__ route,
    const float* __restrict__ qa, const float* __restrict__ va,
    float* __restrict__ low, int n)
{
    constexpr int DR = DD / DSPLIT;
    int e  = blockIdx.x;
    int t0 = blockIdx.y * TILE;
    int ds = blockIdx.z;

    __shared__ int   sel_tok[TILE];
    __shared__ float sel_w[TILE];
    __shared__ int   sel_k[TILE];
    __shared__ int   sm_cnt;
    if (threadIdx.x == 0) sm_cnt = 0;
    __syncthreads();
    for (int i = threadIdx.x; i < TILE; i += 256) {
        int tok = t0 + i;
        if (tok < n) {
            Route rt = route[tok];
            if (rt.i0 == e) {
                int p = atomicAdd(&sm_cnt, 1);
                sel_tok[p] = tok; sel_w[p] = rt.w0; sel_k[p] = 0;
            } else if (rt.i1 == e) {
                int p = atomicAdd(&sm_cnt, 1);
                sel_tok[p] = tok; sel_w[p] = rt.w1; sel_k[p] = 1;
            }
        }
    }
    __syncthreads();
    int m = sm_cnt;
    if (m == 0) return;

    __align__(16) __shared__ float a_s[(TWOPASS ? 1 : 2) * DR * RR];
    __align__(16) __shared__ float hs[BATCH * DR];

    const float* aq_e = qa + (size_t)e * DD * RR + (size_t)ds * DR * RR;
    const float* av_e = va + (size_t)e * DD * RR + (size_t)ds * DR * RR;

    int s    = threadIdx.x & 15;   // d-slice within 16
    int tile = threadIdx.x >> 4;
    int tp   = tile >> 2;          // token group (== wave id)
    int rp   = tile & 3;           // rank group

    constexpr int NMAT = TWOPASS ? 2 : 1;
    for (int mat = 0; mat < NMAT; ++mat) {
        __syncthreads();           // prior readers of a_s / hs done
        if (TWOPASS) {
            const float* ap = mat ? av_e : aq_e;
            for (int t = threadIdx.x; t < DR * RR / 4; t += 256) {
                int d = t >> 2, rf = (t & 3) * 4;
                *(float4*)&a_s[d * RR + rf] = *(const float4*)&ap[(size_t)d * RR + rf];
            }
        } else {
            for (int t = threadIdx.x; t < 2 * DR * RR / 4; t += 256) {
                int which = t >= DR * RR / 4;
                int tt = which ? t - DR * RR / 4 : t;
                int d = tt >> 2, rf = (tt & 3) * 4;
                const float* ap = which ? av_e : aq_e;
                *(float4*)&a_s[which * DR * RR + d * RR + rf] =
                    *(const float4*)&ap[(size_t)d * RR + rf];
            }
        }

        for (int b0 = 0; b0 < m; b0 += BATCH) {
            int mb = min(BATCH, m - b0);
            __syncthreads();       // prev batch compute done; publishes a_s too
            for (int t = threadIdx.x; t < BATCH * DR / 4; t += 256) {
                int j = t / (DR / 4), f = (t % (DR / 4)) * 4;
                float4 v = make_float4(0.f, 0.f, 0.f, 0.f);
                if (j < mb)
                    v = *(const float4*)&h[(size_t)sel_tok[b0 + j] * DD + ds * DR + f];
                *(float4*)&hs[j * DR + f] = v;
            }
            __syncthreads();

            if (!TWOPASS) {
                float accq[4][4] = {}, accv[4][4] = {};
#pragma unroll
                for (int dd = 0; dd < DR / 16; ++dd) {
                    int d = dd * 16 + s;
                    float4 a0 = *(const float4*)&a_s[d * RR + rp * 4];
                    float4 a1 = *(const float4*)&a_s[DR * RR + d * RR + rp * 4];
                    float hv[4];
#pragma unroll
                    for (int ti = 0; ti < 4; ++ti)
                        hv[ti] = hs[(tp * 4 + ti) * DR + d];
                    const float* q4 = &a0.x;
                    const float* v4 = &a1.x;
#pragma unroll
                    for (int ti = 0; ti < 4; ++ti)
#pragma unroll
                        for (int ri = 0; ri < 4; ++ri) {
                            accq[ti][ri] = fmaf(hv[ti], q4[ri], accq[ti][ri]);
                            accv[ti][ri] = fmaf(hv[ti], v4[ri], accv[ti][ri]);
                        }
                }
#pragma unroll
                for (int ti = 0; ti < 4; ++ti)
#pragma unroll
                    for (int ri = 0; ri < 4; ++ri) {
#pragma unroll
                        for (int off = 8; off; off >>= 1) {
                            accq[ti][ri] += __shfl_down(accq[ti][ri], off, 16);
                            accv[ti][ri] += __shfl_down(accv[ti][ri], off, 16);
                        }
                    }
                if (s == 0) {
#pragma unroll
                    for (int ti = 0; ti < 4; ++ti) {
                        int t = tp * 4 + ti;
                        if (t < mb) {
                            int   tok = sel_tok[b0 + t];
                            int   k   = sel_k[b0 + t];
                            float w   = sel_w[b0 + t];
                            float* dst = low + ((size_t)(tok * 2 + k) * DSPLIT + ds) * 32;
                            float4 vq = make_float4(accq[ti][0]*w, accq[ti][1]*w,
                                                    accq[ti][2]*w, accq[ti][3]*w);
                            float4 vv = make_float4(accv[ti][0]*w, accv[ti][1]*w,
                                                    accv[ti][2]*w, accv[ti][3]*w);
                            *(float4*)&dst[rp * 4]      = vq;
                            *(float4*)&dst[16 + rp * 4] = vv;
                        }
                    }
                }
            } else {
                float acc[4][4] = {};
#pragma unroll
                for (int dd = 0; dd < DR / 16; ++dd) {
                    int d = dd * 16 + s;
                    float4 a0 = *(const float4*)&a_s[d * RR + rp * 4];
                    float hv[4];
#pragma unroll
                    for (int ti = 0; ti < 4; ++ti)
                        hv[ti] = hs[(tp * 4 + ti) * DR + d];
                    const float* q4 = &a0.x;
#pragma unroll
                    for (int ti = 0; ti < 4; ++ti)
#pragma unroll
                        for (int ri = 0; ri < 4; ++ri)
                            acc[ti][ri] = fmaf(hv[ti], q4[ri], acc[ti][ri]);
                }
#pragma unroll
                for (int ti = 0; ti < 4; ++ti)
#pragma unroll
                    for (int ri = 0; ri < 4; ++ri) {
#pragma unroll
                        for (int off = 8; off; off >>= 1)
                            acc[ti][ri] += __shfl_down(acc[ti][ri], off, 16);
                    }
                if (s == 0) {
#pragma unroll
                    for (int ti = 0; ti < 4; ++ti) {
                        int t = tp * 4 + ti;
                        if (t < mb) {
                            int   tok = sel_tok[b0 + t];
                            int   k   = sel_k[b0 + t];
                            float w   = sel_w[b0 + t];
                            float* dst = low + ((size_t)(tok * 2 + k) * DSPLIT + ds) * 32
                                       + mat * 16;
                            float4 vq = make_float4(acc[ti][0]*w, acc[ti][1]*w,
                                                    acc[ti][2]*w, acc[ti][3]*w);
                            *(float4*)&dst[rp * 4] = vq;
                        }
                    }
                }
            }
        }
    }
}

// ---------------- K3: B-side, token-major bucketed, bc double-buffered -----
template<int DSPLIT>
__global__ __launch_bounds__(256) void b_kernel(
    const Route* __restrict__ route, const float* __restrict__ low,
    const float* __restrict__ qb, const float* __restrict__ vb,
    float* __restrict__ outq, float* __restrict__ outv, int n)
{
    int t0 = blockIdx.x * T2;
    int cg = blockIdx.y;               // 0..7 -> q cols, 8..9 -> v cols
    int tid = threadIdx.x;

    __shared__ float acc_s[T2 * 256];  // 32 KB
    __shared__ float ls[T2 * 2 * RR];  // 4 KB
    __shared__ int   elist[EE * T2];   // 2 KB
    __shared__ int   ecnt[EE];
    __shared__ int   plist[EE];
    __shared__ int   pcnt;
    __shared__ Route rts[T2];

    if (tid < EE) ecnt[tid] = 0;
    if (tid == 0) pcnt = 0;
    if (tid < T2) {
        int tok = t0 + tid;
        Route rt; rt.i0 = -1; rt.i1 = -1; rt.w0 = 0.f; rt.w1 = 0.f;
        if (tok < n) rt = route[tok];
        rts[tid] = rt;
    }
    __syncthreads();
    if (tid < T2 * 2) {
        int j = tid >> 1, k = tid & 1;
        int e = k ? rts[j].i1 : rts[j].i0;
        if (e >= 0) {
            int p = atomicAdd(&ecnt[e], 1);
            elist[e * T2 + p] = j * 2 + k;
        }
    }
    int side = (cg >= CGQ) ? 1 : 0;
    {   // stage ls: 64 slots x 4 float4 == 256 tasks == 1/thread
        int slot = tid >> 2, r4 = (tid & 3) * 4;
        int j = slot >> 1;
        float4 v = make_float4(0.f, 0.f, 0.f, 0.f);
        if (t0 + j < n) {
            const float* lp = low + (size_t)((t0 + j) * 2 + (slot & 1)) * (DSPLIT * 32)
                            + side * 16 + r4;
#pragma unroll
            for (int p = 0; p < DSPLIT; ++p) {
                float4 q = *(const float4*)(lp + p * 32);
                v.x += q.x; v.y += q.y; v.z += q.z; v.w += q.w;
            }
        }
        *(float4*)&ls[slot * RR + r4] = v;
    }
#pragma unroll
    for (int j = 0; j < T2; ++j) acc_s[j * 256 + tid] = 0.f;
    __syncthreads();
    if (tid < EE && ecnt[tid] > 0) { int p = atomicAdd(&pcnt, 1); plist[p] = tid; }
    __syncthreads();
    int P = pcnt;

    const float* bp; float* outp; int W, colbase;
    if (cg < CGQ) { bp = qb; outp = outq; W = QO; colbase = cg * 256; }
    else          { bp = vb; outp = outv; W = VO; colbase = (cg - CGQ) * 256; }
    int col = colbase + tid;

    if (P > 0) {
        float bc[RR];
        {
            const float* be = bp + (size_t)plist[0] * RR * W + col;
#pragma unroll
            for (int r = 0; r < RR; ++r) bc[r] = be[(size_t)r * W];
        }
        for (int p = 0; p < P; ++p) {
            float bn[RR];
            if (p + 1 < P) {
                const float* be = bp + (size_t)plist[p + 1] * RR * W + col;
#pragma unroll
                for (int r = 0; r < RR; ++r) bn[r] = be[(size_t)r * W];
            }
            int e = plist[p], c = ecnt[e];
            for (int ii = 0; ii < c; ++ii) {
                int sk = elist[e * T2 + ii];
                int j  = sk >> 1;
                const float* lp = &ls[sk * RR];
                float4 l0 = *(const float4*)(lp);
                float4 l1 = *(const float4*)(lp + 4);
                float4 l2 = *(const float4*)(lp + 8);
                float4 l3 = *(const float4*)(lp + 12);
                float v = 0.f;
                v = fmaf(l0.x, bc[0],  v); v = fmaf(l0.y, bc[1],  v);
                v = fmaf(l0.z, bc[2],  v); v = fmaf(l0.w, bc[3],  v);
                v = fmaf(l1.x, bc[4],  v); v = fmaf(l1.y, bc[5],  v);
                v = fmaf(l1.z, bc[6],  v); v = fmaf(l1.w, bc[7],  v);
                v = fmaf(l2.x, bc[8],  v); v = fmaf(l2.y, bc[9],  v);
                v = fmaf(l2.z, bc[10], v); v = fmaf(l2.w, bc[11], v);
                v = fmaf(l3.x, bc[12], v); v = fmaf(l3.y, bc[13], v);
                v = fmaf(l3.z, bc[14], v); v = fmaf(l3.w, bc[15], v);
                acc_s[j * 256 + tid] += v;   // thread-private column
            }
            if (p + 1 < P) {
#pragma unroll
                for (int r = 0; r < RR; ++r) bc[r] = bn[r];
            }
        }
    }
    __syncthreads();
    // vectorized store: 32 tok x 64 float4 == 2048 tasks, 8/thread;
    // each wave stores one full contiguous 1KB token row segment.
    for (int t = tid; t < T2 * 64; t += 256) {
        int j = t >> 6, fq = (t & 63) * 4;
        int tok = t0 + j;
        if (tok < n) {
            float4 v = *(const float4*)&acc_s[j * 256 + fq];
            *(float4*)&outp[(size_t)tok * W + colbase + fq] = v;
        }
    }
}

extern "C" void kernel_launch(void* const* d_in, const int* in_sizes, int n_in,
                              void* d_out, int out_size, void* d_ws, size_t ws_size,
                              hipStream_t stream) {
    const float* h  = (const float*)d_in[0];
    const float* rw = (const float*)d_in[1];
    const float* qa = (const float*)d_in[2];
    const float* qb = (const float*)d_in[3];
    const float* va = (const float*)d_in[4];
    const float* vb = (const float*)d_in[5];

    int n = in_sizes[0] / DD;
    float* out  = (float*)d_out;
    float* outq = out;
    float* outv = out + (size_t)n * QO;

    size_t route_b = ((size_t)n * 16 + 255) & ~(size_t)255;
    Route* route = (Route*)d_ws;
    float* low   = (float*)((char*)d_ws + route_b);
    size_t need8 = route_b + (size_t)n * 2 * 8 * 32 * 4;   // 8 MB @ n=4096

    int tiles = (n + TILE - 1) / TILE;
    router_kernel<<<(n + RTB - 1) / RTB, 256, 0, stream>>>(h, rw, route, n);

    dim3 g3((n + T2 - 1) / T2, CGQ + CGV);
    if (ws_size >= need8) {
        dim3 g2(EE, tiles, 8);
        a_kernel<8, false><<<g2, 256, 0, stream>>>(h, route, qa, va, low, n);
        b_kernel<8><<<g3, 256, 0, stream>>>(route, low, qb, vb, outq, outv, n);
    } else {
        dim3 g2(EE, tiles, 4);
        a_kernel<4, true><<<g2, 256, 0, stream>>>(h, route, qa, va, low, n);
        b_kernel<4><<<g3, 256, 0, stream>>>(route, low, qb, vb, outq, outv, n);
    }
}